// Round 18
// baseline (4935.441 us; speedup 1.0000x reference)
//
#include <hip/hip_runtime.h>
#include <stdint.h>

// R18 = R15 (best PASS, 408us/win) + two body-side changes:
//  (1) HOT POLL: s_sleep(1) replaced by ~48-deep dependent-FMA backoff.
//      Hypothesis (fits all R10-R17 data): recur is ~96% idle for 3.3ms =>
//      DPM clock floor (~500-600MHz); body cycle model (~2000cyc) matches
//      3.2us at low clock, 0.9us at 2.4GHz. Keeping every SIMD issuing VALU
//      work should ramp the clock; the chain also spaces L3 poll retries.
//  (2) ONE barrier/step: xchg double-buffered by step parity. Reads of buf b
//      at step ts complete before that thread's BAR(ts+1); writes of buf b
//      at step ts+2 start after BAR(ts+1) => WAR-safe with a single barrier.
// Protocol/mappings byte-identical to R15 otherwise (tagged h words, zeroed
// every launch; 256 blocks x 512 thr; wave = K-slice-128; bfr[4][4]).

typedef unsigned short u16;
typedef __attribute__((ext_vector_type(8))) short bf16x8;
typedef __attribute__((ext_vector_type(2))) uint64_t u64x2;
typedef __attribute__((ext_vector_type(4))) float f32x4;

static __device__ __forceinline__ u16 f2b(float f) {
  uint32_t b = __float_as_uint(f);
  return (u16)((b + 0x7fffu + ((b >> 16) & 1u)) >> 16);  // RNE
}
static __device__ __forceinline__ uint64_t pack4(float4 v) {
  return (uint64_t)f2b(v.x) | ((uint64_t)f2b(v.y) << 16) |
         ((uint64_t)f2b(v.z) << 32) | ((uint64_t)f2b(v.w) << 48);
}
static __device__ __forceinline__ float b2f(u16 u) {
  return __uint_as_float(((uint32_t)u) << 16);
}
static __device__ __forceinline__ float sigm(float x) {
  return 1.0f / (1.0f + __expf(-x));
}
static __device__ __forceinline__ float tanh_(float x) {
  float e = __expf(2.0f * x);
  return 1.0f - 2.0f / (e + 1.0f);
}

// ---------------------------------------------------------------- prep kernels
__global__ __launch_bounds__(256) void transpose_w(const float* __restrict__ Wih,
                                                   const float* __restrict__ Whh,
                                                   u16* __restrict__ Tih,
                                                   u16* __restrict__ Thh) {
  __shared__ float tile[64][65];
  const float* src = blockIdx.z ? Whh : Wih;
  u16* dst = blockIdx.z ? Thh : Tih;
  int k0 = blockIdx.y * 64, n0 = blockIdx.x * 64;
  int tid = threadIdx.x;
#pragma unroll
  for (int i = 0; i < 16; ++i) {
    int idx = i * 256 + tid;
    int kl = idx >> 6, nl = idx & 63;
    tile[kl][nl] = src[(size_t)(k0 + kl) * 4096 + n0 + nl];
  }
  __syncthreads();
#pragma unroll
  for (int i = 0; i < 16; ++i) {
    int idx = i * 256 + tid;
    int nl = idx >> 6, kl = idx & 63;
    dst[(size_t)(n0 + nl) * 1024 + k0 + kl] = f2b(tile[kl][nl]);
  }
}

// h0 [64][1024] f32 -> tagged words (tag 0) in h_tag buf 1
__global__ __launch_bounds__(256) void convert_h0(const float* __restrict__ h0,
                                                  uint64_t* __restrict__ dst) {
  int i = blockIdx.x * 256 + threadIdx.x;  // 32768 words
  float2 v = ((const float2*)h0)[i];
  uint32_t pair = (uint32_t)f2b(v.x) | ((uint32_t)f2b(v.y) << 16);
  dst[i] = (uint64_t)pair;  // tag = 0
}

// ------------------------------------------------------------------- big GEMM
// C[M][4096] bf16 = A[M][1024] f32 @ Bt[4096][1024]^T + bias. (unchanged, PASS)
__global__ __launch_bounds__(256) void gemm_xg(const float* __restrict__ A,
                                               const u16* __restrict__ Bt,
                                               const float* __restrict__ bias,
                                               u16* __restrict__ C) {
  __shared__ u16 sA[2][128 * 32];
  __shared__ u16 sB[2][128 * 32];
  const int tid = threadIdx.x;
  const int wave = tid >> 6, lane = tid & 63;
  const int bx = blockIdx.x, by = blockIdx.y;
  const int wr = wave >> 1, wc = wave & 1;
  const int lm = lane & 15, ko = (lane >> 4) * 8;

  const int ar = lane >> 1, ac = (lane & 1) * 16;
  const float* gA = A + (size_t)(by * 128 + wave * 32 + ar) * 1024 + ac;
  const u16* gB = Bt + (size_t)(bx * 128 + wave * 32 + (lane >> 2)) * 1024 + (lane & 3) * 8;
  const int bidx = wave * 1024 + (lane >> 2) * 32 + (lane & 3) * 8;

  f32x4 acc[4][4] = {};

  auto stage = [&](int kt, int buf) {
    const u16* gb = gB + kt * 32;
    bf16x8 b0 = *(const bf16x8*)gb;
    bf16x8 b1 = *(const bf16x8*)(gb + 16 * 1024);
    *(bf16x8*)&sB[buf][bidx] = b0;
    *(bf16x8*)&sB[buf][bidx + 512] = b1;
    const float* ga = gA + kt * 32;
    float4 v0 = *(const float4*)(ga + 0);
    float4 v1 = *(const float4*)(ga + 4);
    float4 v2 = *(const float4*)(ga + 8);
    float4 v3 = *(const float4*)(ga + 12);
    uint64_t* la = (uint64_t*)&sA[buf][wave * 1024 + ar * 32 + ac];
    la[0] = pack4(v0);
    la[1] = pack4(v1);
    la[2] = pack4(v2);
    la[3] = pack4(v3);
  };

  stage(0, 0);
  __syncthreads();
  int p = 0;
  for (int kt = 0; kt < 32; ++kt) {
    if (kt < 31) stage(kt + 1, p ^ 1);
    bf16x8 af[4], bfv[4];
#pragma unroll
    for (int i = 0; i < 4; ++i)
      af[i] = *(const bf16x8*)&sA[p][(wr * 64 + i * 16 + lm) * 32 + ko];
#pragma unroll
    for (int j = 0; j < 4; ++j)
      bfv[j] = *(const bf16x8*)&sB[p][(wc * 64 + j * 16 + lm) * 32 + ko];
#pragma unroll
    for (int i = 0; i < 4; ++i)
#pragma unroll
      for (int j = 0; j < 4; ++j)
        acc[i][j] = __builtin_amdgcn_mfma_f32_16x16x32_bf16(af[i], bfv[j], acc[i][j], 0, 0, 0);
    __syncthreads();
    p ^= 1;
  }

  float bj[4];
#pragma unroll
  for (int j = 0; j < 4; ++j)
    bj[j] = bias[bx * 128 + wc * 64 + j * 16 + lm];
#pragma unroll
  for (int i = 0; i < 4; ++i) {
    int row = by * 128 + wr * 64 + i * 16 + (lane >> 4) * 4;
#pragma unroll
    for (int j = 0; j < 4; ++j) {
      int col = bx * 128 + wc * 64 + j * 16 + lm;
#pragma unroll
      for (int r = 0; r < 4; ++r)
        C[(size_t)(row + r) * 4096 + col] = f2b(acc[i][j][r] + bj[j]);
    }
  }
}

// --------------------------------------- persistent tagged-h recurrence
// Grid 256 blocks (1/CU), block 512 (8 waves). bid: un=bid&63 (units
// un*16..+16), bq=bid>>6 (batch rows bq*16..+16). 64 gate-cols/block:
// c = nt*16+lm (nt==gate). Wave w = K-slice [w*128,+128): bfr[kk][nt]
// 64 VGPRs; A-frag = 16 tagged u64 words polled directly (tag >= t).
__global__ __launch_bounds__(512, 1) void recur_pers(
    const u16* __restrict__ xg,        // [W][64][4096] bf16, bias added
    const u16* __restrict__ whh_t,     // [4096][1024] bf16
    uint64_t* __restrict__ h_tag,      // [2][64][512] tagged words
    float* __restrict__ c_st,          // [64][1024] f32
    float* __restrict__ out_h,         // [512][64][1024] f32
    float* __restrict__ out_hT, float* __restrict__ out_cT,
    int t0, int W) {
  __shared__ float xchg[2][8][16][68];  // step-parity double buffer

  const int tid = threadIdx.x;
  const int wave = tid >> 6, lane = tid & 63;
  const int bid = blockIdx.x;
  const int un = bid & 63;
  const int bq = bid >> 6;
  const int lm = lane & 15, hi = lane >> 4;

  // ---- W_hh B-frags resident: bfr[kk][nt]; row = nt*1024 + un*16 + lm ----
  bf16x8 bfr[4][4];
#pragma unroll
  for (int nt = 0; nt < 4; ++nt) {
    const u16* bp = whh_t + (size_t)(nt * 1024 + un * 16 + lm) * 1024 + wave * 128 + hi * 8;
#pragma unroll
    for (int kk = 0; kk < 4; ++kk) bfr[kk][nt] = *(const bf16x8*)(bp + kk * 32);
  }

  // ---- epilogue ownership: tid<256 -> (row r_b, unit u) ----
  const int r_b = tid >> 4, u = tid & 15;
  const int b = bq * 16 + r_b;
  const int unit = un * 16 + u;
  float c_val = (tid < 256) ? c_st[b * 1024 + unit] : 0.f;

  const int b_row = bq * 16 + lm;  // A-frag batch row for this lane
  float warm = 1.0f + (float)tid;  // clock-warming accumulator (kept live)

  for (int ts = 0; ts < W; ++ts) {
    const int t = t0 + ts;

    // ---- xg loads first (independent; complete under the poll) ----
    u16 xr0 = 0, xr1 = 0, xr2 = 0, xr3 = 0;
    if (tid < 256) {
      const u16* xgp = xg + ((size_t)ts * 64 + b) * 4096 + unit;
      xr0 = xgp[0];
      xr1 = xgp[1024];
      xr2 = xgp[2048];
      xr3 = xgp[3072];
    }

    // ---- poll the 16 tagged words of my A-frag (tag >= t), HOT backoff ----
    const uint64_t* hb = h_tag + ((size_t)((t - 1) & 1) * 64 + b_row) * 512 +
                         wave * 64 + hi * 4;
    uint64_t wbuf[16];
    {
      uint32_t spin = 0;
      bool ok = false;
      for (; spin < (1u << 15); ++spin) {  // bounded: never wedge
#pragma unroll
        for (int kk = 0; kk < 4; ++kk)
#pragma unroll
          for (int j = 0; j < 4; ++j)
            wbuf[kk * 4 + j] = __hip_atomic_load(hb + kk * 16 + j, __ATOMIC_RELAXED,
                                                 __HIP_MEMORY_SCOPE_AGENT);
        bool good = true;
#pragma unroll
        for (int i = 0; i < 16; ++i)
          good &= ((uint32_t)(wbuf[i] >> 32) >= (uint32_t)t);
        if (__all(good)) { ok = true; break; }
        // VALU-warm backoff (~200 cyc): keeps SIMD busy -> DPM clock up,
        // and spaces L3 poll retries (replaces s_sleep).
#pragma unroll
        for (int z = 0; z < 48; ++z) warm = __builtin_fmaf(warm, 0.99999988f, 1.0e-7f);
      }
      if (!ok && lane == 0)  // sentinel: absmax ~1e6 => protocol stall
        out_h[(size_t)t * 65536 + bid] = 1.0e6f;
    }

    // ---- extract payload -> 4 A-frags; 16 MFMAs (4 chains of 4) ----
    f32x4 acc[4] = {};
#pragma unroll
    for (int kk = 0; kk < 4; ++kk) {
      u64x2 v;
      v.x = (uint64_t)(uint32_t)wbuf[kk * 4 + 0] |
            ((uint64_t)(uint32_t)wbuf[kk * 4 + 1] << 32);
      v.y = (uint64_t)(uint32_t)wbuf[kk * 4 + 2] |
            ((uint64_t)(uint32_t)wbuf[kk * 4 + 3] << 32);
      bf16x8 a = __builtin_bit_cast(bf16x8, v);
#pragma unroll
      for (int nt = 0; nt < 4; ++nt)
        acc[nt] = __builtin_amdgcn_mfma_f32_16x16x32_bf16(a, bfr[kk][nt], acc[nt], 0, 0, 0);
    }
    {
      int crow = hi * 4;  // C layout: col=lane&15, row=(lane>>4)*4+r
#pragma unroll
      for (int nt = 0; nt < 4; ++nt)
#pragma unroll
        for (int r = 0; r < 4; ++r) xchg[ts & 1][wave][crow + r][nt * 16 + lm] = acc[nt][r];
    }
    __syncthreads();  // the step's ONLY barrier (dbuf covers xchg WAR)

    if (tid < 256) {
      float raw[4];
#pragma unroll
      for (int g = 0; g < 4; ++g) {
        int c = g * 16 + u;
        float s = xchg[ts & 1][0][r_b][c];
#pragma unroll
        for (int w = 1; w < 8; ++w) s += xchg[ts & 1][w][r_b][c];
        raw[g] = s;
      }
      float ig = sigm(raw[0] + b2f(xr0));
      float fg = sigm(raw[1] + b2f(xr1));
      float gg = tanh_(raw[2] + b2f(xr2));
      float og = sigm(raw[3] + b2f(xr3));
      c_val = fg * c_val + ig * gg;
      float h_new = og * tanh_(c_val);
      // tagged store: ONE atomic u64 = payload pair | (t+1)<<32
      uint32_t mine = f2b(h_new);
      uint32_t other = __shfl_xor(mine, 1);
      if ((u & 1) == 0) {
        uint64_t word = (uint64_t)(mine | (other << 16)) | ((uint64_t)(uint32_t)(t + 1) << 32);
        __hip_atomic_store(
            h_tag + ((size_t)(t & 1) * 64 + b) * 512 + (unit >> 1), word,
            __ATOMIC_RELAXED, __HIP_MEMORY_SCOPE_AGENT);
      }
      out_h[(size_t)t * 65536 + (size_t)b * 1024 + unit] = h_new;
      if (t == 511) {
        out_hT[b * 1024 + unit] = h_new;
        out_cT[b * 1024 + unit] = c_val;
      }
    }
  }

  if (tid < 256) c_st[b * 1024 + unit] = c_val;
  if (warm == 123.456f) out_cT[0] = warm;  // keep warm-chain live (never true)
}

// -------------------------------------------------------------------- launch
extern "C" void kernel_launch(void* const* d_in, const int* in_sizes, int n_in,
                              void* d_out, int out_size, void* d_ws, size_t ws_size,
                              hipStream_t stream) {
  const float* x = (const float*)d_in[0];
  const float* h0 = (const float*)d_in[1];
  const float* c0 = (const float*)d_in[2];
  const float* wih = (const float*)d_in[3];
  const float* whh = (const float*)d_in[4];
  const float* bias = (const float*)d_in[5];

  float* out = (float*)d_out;
  float* out_h = out;                              // [512][64][1024]
  float* out_hT = out + (size_t)512 * 64 * 1024;   // [64][1024]
  float* out_cT = out_hT + 64 * 1024;              // [64][1024]

  // adaptive xg window (bf16): W in {64,16,4}
  const size_t fixed = (size_t)2 * 4096 * 1024 * 2    // wih_t + whh_t
                       + (size_t)2 * 64 * 512 * 8     // h_tag (512KB)
                       + (size_t)64 * 1024 * 4;       // c_state
  int W = 64;
  while (W > 4 && fixed + (size_t)W * 64 * 4096 * 2 > ws_size) W >>= 2;

  char* ws = (char*)d_ws;
  u16* wih_t = (u16*)ws;     ws += (size_t)4096 * 1024 * 2;    // 8MB
  u16* whh_t = (u16*)ws;     ws += (size_t)4096 * 1024 * 2;    // 8MB
  u16* xg = (u16*)ws;        ws += (size_t)W * 64 * 4096 * 2;  // <=32MB
  uint64_t* h_tag = (uint64_t*)ws; ws += (size_t)2 * 64 * 512 * 8;  // 512KB
  float* c_st = (float*)ws;                                    // 256KB

  // tags must start below any future t (0xAA poison / replay staleness)
  hipMemsetAsync(h_tag, 0, (size_t)2 * 64 * 512 * 8, stream);
  convert_h0<<<128, 256, 0, stream>>>(h0, h_tag + (size_t)64 * 512);  // buf 1
  hipMemcpyAsync(c_st, c0, (size_t)64 * 1024 * 4, hipMemcpyDeviceToDevice, stream);
  transpose_w<<<dim3(64, 16, 2), 256, 0, stream>>>(wih, whh, wih_t, whh_t);

  for (int t0 = 0; t0 < 512; t0 += W) {
    gemm_xg<<<dim3(32, W / 2), 256, 0, stream>>>(x + (size_t)t0 * 64 * 1024, wih_t, bias, xg);
    int t0c = t0, Wc = W;
    void* args[] = {(void*)&xg,    (void*)&whh_t,  (void*)&h_tag, (void*)&c_st,
                    (void*)&out_h, (void*)&out_hT, (void*)&out_cT,
                    (void*)&t0c,   (void*)&Wc};
    hipLaunchCooperativeKernel((const void*)recur_pers, dim3(256), dim3(512), args, 0,
                               stream);
  }
}

// Round 19
// 4024.121 us; speedup vs baseline: 1.2265x; 1.2265x over previous
//
#include <hip/hip_runtime.h>
#include <stdint.h>

// R19 = R15 (best PASS, 408us/win) with ONE mechanism changed: the two
// __syncthreads() in the step loop are replaced by raw s_barrier with
// lgkmcnt(0)-only waits. Rationale: __syncthreads compiles to
// "s_waitcnt vmcnt(0) lgkmcnt(0); s_barrier" — every step serially eats the
// HBM out_h store ack (~900+cy) and h_tag L3 store ack inside the body.
// That drain is the one cost present in EVERY R9-R18 variant (the invariant
// ~3.2us body). LDS ordering (xchg write->read, read->next-write) only needs
// lgkmcnt(0); h_tag words are self-validating (tagged), out_h is pure output
// drained at kernel end. sched_barrier(0) fences compiler reordering
// (rule #18). Everything else byte-identical to R15.

typedef unsigned short u16;
typedef __attribute__((ext_vector_type(8))) short bf16x8;
typedef __attribute__((ext_vector_type(2))) uint64_t u64x2;
typedef __attribute__((ext_vector_type(4))) float f32x4;

// raw barrier: LDS-only drain (no vmcnt!) + compiler fences
#define BAR_LDS()                                        \
  do {                                                   \
    __builtin_amdgcn_sched_barrier(0);                   \
    asm volatile("s_waitcnt lgkmcnt(0)" ::: "memory");   \
    __builtin_amdgcn_s_barrier();                        \
    __builtin_amdgcn_sched_barrier(0);                   \
  } while (0)

static __device__ __forceinline__ u16 f2b(float f) {
  uint32_t b = __float_as_uint(f);
  return (u16)((b + 0x7fffu + ((b >> 16) & 1u)) >> 16);  // RNE
}
static __device__ __forceinline__ uint64_t pack4(float4 v) {
  return (uint64_t)f2b(v.x) | ((uint64_t)f2b(v.y) << 16) |
         ((uint64_t)f2b(v.z) << 32) | ((uint64_t)f2b(v.w) << 48);
}
static __device__ __forceinline__ float b2f(u16 u) {
  return __uint_as_float(((uint32_t)u) << 16);
}
static __device__ __forceinline__ float sigm(float x) {
  return 1.0f / (1.0f + __expf(-x));
}
static __device__ __forceinline__ float tanh_(float x) {
  float e = __expf(2.0f * x);
  return 1.0f - 2.0f / (e + 1.0f);
}

// ---------------------------------------------------------------- prep kernels
__global__ __launch_bounds__(256) void transpose_w(const float* __restrict__ Wih,
                                                   const float* __restrict__ Whh,
                                                   u16* __restrict__ Tih,
                                                   u16* __restrict__ Thh) {
  __shared__ float tile[64][65];
  const float* src = blockIdx.z ? Whh : Wih;
  u16* dst = blockIdx.z ? Thh : Tih;
  int k0 = blockIdx.y * 64, n0 = blockIdx.x * 64;
  int tid = threadIdx.x;
#pragma unroll
  for (int i = 0; i < 16; ++i) {
    int idx = i * 256 + tid;
    int kl = idx >> 6, nl = idx & 63;
    tile[kl][nl] = src[(size_t)(k0 + kl) * 4096 + n0 + nl];
  }
  __syncthreads();
#pragma unroll
  for (int i = 0; i < 16; ++i) {
    int idx = i * 256 + tid;
    int nl = idx >> 6, kl = idx & 63;
    dst[(size_t)(n0 + nl) * 1024 + k0 + kl] = f2b(tile[kl][nl]);
  }
}

// h0 [64][1024] f32 -> tagged words (tag 0) in h_tag buf 1
__global__ __launch_bounds__(256) void convert_h0(const float* __restrict__ h0,
                                                  uint64_t* __restrict__ dst) {
  int i = blockIdx.x * 256 + threadIdx.x;  // 32768 words
  float2 v = ((const float2*)h0)[i];
  uint32_t pair = (uint32_t)f2b(v.x) | ((uint32_t)f2b(v.y) << 16);
  dst[i] = (uint64_t)pair;  // tag = 0
}

// ------------------------------------------------------------------- big GEMM
// C[M][4096] bf16 = A[M][1024] f32 @ Bt[4096][1024]^T + bias. (unchanged, PASS)
__global__ __launch_bounds__(256) void gemm_xg(const float* __restrict__ A,
                                               const u16* __restrict__ Bt,
                                               const float* __restrict__ bias,
                                               u16* __restrict__ C) {
  __shared__ u16 sA[2][128 * 32];
  __shared__ u16 sB[2][128 * 32];
  const int tid = threadIdx.x;
  const int wave = tid >> 6, lane = tid & 63;
  const int bx = blockIdx.x, by = blockIdx.y;
  const int wr = wave >> 1, wc = wave & 1;
  const int lm = lane & 15, ko = (lane >> 4) * 8;

  const int ar = lane >> 1, ac = (lane & 1) * 16;
  const float* gA = A + (size_t)(by * 128 + wave * 32 + ar) * 1024 + ac;
  const u16* gB = Bt + (size_t)(bx * 128 + wave * 32 + (lane >> 2)) * 1024 + (lane & 3) * 8;
  const int bidx = wave * 1024 + (lane >> 2) * 32 + (lane & 3) * 8;

  f32x4 acc[4][4] = {};

  auto stage = [&](int kt, int buf) {
    const u16* gb = gB + kt * 32;
    bf16x8 b0 = *(const bf16x8*)gb;
    bf16x8 b1 = *(const bf16x8*)(gb + 16 * 1024);
    *(bf16x8*)&sB[buf][bidx] = b0;
    *(bf16x8*)&sB[buf][bidx + 512] = b1;
    const float* ga = gA + kt * 32;
    float4 v0 = *(const float4*)(ga + 0);
    float4 v1 = *(const float4*)(ga + 4);
    float4 v2 = *(const float4*)(ga + 8);
    float4 v3 = *(const float4*)(ga + 12);
    uint64_t* la = (uint64_t*)&sA[buf][wave * 1024 + ar * 32 + ac];
    la[0] = pack4(v0);
    la[1] = pack4(v1);
    la[2] = pack4(v2);
    la[3] = pack4(v3);
  };

  stage(0, 0);
  __syncthreads();
  int p = 0;
  for (int kt = 0; kt < 32; ++kt) {
    if (kt < 31) stage(kt + 1, p ^ 1);
    bf16x8 af[4], bfv[4];
#pragma unroll
    for (int i = 0; i < 4; ++i)
      af[i] = *(const bf16x8*)&sA[p][(wr * 64 + i * 16 + lm) * 32 + ko];
#pragma unroll
    for (int j = 0; j < 4; ++j)
      bfv[j] = *(const bf16x8*)&sB[p][(wc * 64 + j * 16 + lm) * 32 + ko];
#pragma unroll
    for (int i = 0; i < 4; ++i)
#pragma unroll
      for (int j = 0; j < 4; ++j)
        acc[i][j] = __builtin_amdgcn_mfma_f32_16x16x32_bf16(af[i], bfv[j], acc[i][j], 0, 0, 0);
    __syncthreads();
    p ^= 1;
  }

  float bj[4];
#pragma unroll
  for (int j = 0; j < 4; ++j)
    bj[j] = bias[bx * 128 + wc * 64 + j * 16 + lm];
#pragma unroll
  for (int i = 0; i < 4; ++i) {
    int row = by * 128 + wr * 64 + i * 16 + (lane >> 4) * 4;
#pragma unroll
    for (int j = 0; j < 4; ++j) {
      int col = bx * 128 + wc * 64 + j * 16 + lm;
#pragma unroll
      for (int r = 0; r < 4; ++r)
        C[(size_t)(row + r) * 4096 + col] = f2b(acc[i][j][r] + bj[j]);
    }
  }
}

// --------------------------------------- persistent tagged-h recurrence
// Grid 256 blocks (1/CU), block 512 (8 waves). bid: un=bid&63 (units
// un*16..+16), bq=bid>>6 (batch rows bq*16..+16). 64 gate-cols/block:
// c = nt*16+lm (nt==gate). Wave w = K-slice [w*128,+128): bfr[kk][nt]
// 64 VGPRs; A-frag = 16 tagged u64 words polled directly (tag >= t).
__global__ __launch_bounds__(512, 1) void recur_pers(
    const u16* __restrict__ xg,        // [W][64][4096] bf16, bias added
    const u16* __restrict__ whh_t,     // [4096][1024] bf16
    uint64_t* __restrict__ h_tag,      // [2][64][512] tagged words
    float* __restrict__ c_st,          // [64][1024] f32
    float* __restrict__ out_h,         // [512][64][1024] f32
    float* __restrict__ out_hT, float* __restrict__ out_cT,
    int t0, int W) {
  __shared__ float xchg[8][16][68];  // 34.8KB, padded

  const int tid = threadIdx.x;
  const int wave = tid >> 6, lane = tid & 63;
  const int bid = blockIdx.x;
  const int un = bid & 63;
  const int bq = bid >> 6;
  const int lm = lane & 15, hi = lane >> 4;

  // ---- W_hh B-frags resident: bfr[kk][nt]; row = nt*1024 + un*16 + lm ----
  bf16x8 bfr[4][4];
#pragma unroll
  for (int nt = 0; nt < 4; ++nt) {
    const u16* bp = whh_t + (size_t)(nt * 1024 + un * 16 + lm) * 1024 + wave * 128 + hi * 8;
#pragma unroll
    for (int kk = 0; kk < 4; ++kk) bfr[kk][nt] = *(const bf16x8*)(bp + kk * 32);
  }

  // ---- epilogue ownership: tid<256 -> (row r_b, unit u) ----
  const int r_b = tid >> 4, u = tid & 15;
  const int b = bq * 16 + r_b;
  const int unit = un * 16 + u;
  float c_val = (tid < 256) ? c_st[b * 1024 + unit] : 0.f;

  const int b_row = bq * 16 + lm;  // A-frag batch row for this lane

  for (int ts = 0; ts < W; ++ts) {
    const int t = t0 + ts;

    // ---- xg loads first (independent; complete under the poll) ----
    u16 xr0 = 0, xr1 = 0, xr2 = 0, xr3 = 0;
    if (tid < 256) {
      const u16* xgp = xg + ((size_t)ts * 64 + b) * 4096 + unit;
      xr0 = xgp[0];
      xr1 = xgp[1024];
      xr2 = xgp[2048];
      xr3 = xgp[3072];
    }

    // ---- poll the 16 tagged words of my A-frag (tag >= t) ----
    const uint64_t* hb = h_tag + ((size_t)((t - 1) & 1) * 64 + b_row) * 512 +
                         wave * 64 + hi * 4;
    uint64_t wbuf[16];
    {
      uint32_t spin = 0;
      bool ok = false;
      for (; spin < (1u << 15); ++spin) {  // bounded: never wedge
#pragma unroll
        for (int kk = 0; kk < 4; ++kk)
#pragma unroll
          for (int j = 0; j < 4; ++j)
            wbuf[kk * 4 + j] = __hip_atomic_load(hb + kk * 16 + j, __ATOMIC_RELAXED,
                                                 __HIP_MEMORY_SCOPE_AGENT);
        bool good = true;
#pragma unroll
        for (int i = 0; i < 16; ++i)
          good &= ((uint32_t)(wbuf[i] >> 32) >= (uint32_t)t);
        if (__all(good)) { ok = true; break; }
        __builtin_amdgcn_s_sleep(1);
      }
      if (!ok && lane == 0)  // sentinel: absmax ~1e6 => protocol stall
        out_h[(size_t)t * 65536 + bid] = 1.0e6f;
    }

    // ---- extract payload -> 4 A-frags; 16 MFMAs (4 chains of 4) ----
    f32x4 acc[4] = {};
#pragma unroll
    for (int kk = 0; kk < 4; ++kk) {
      u64x2 v;
      v.x = (uint64_t)(uint32_t)wbuf[kk * 4 + 0] |
            ((uint64_t)(uint32_t)wbuf[kk * 4 + 1] << 32);
      v.y = (uint64_t)(uint32_t)wbuf[kk * 4 + 2] |
            ((uint64_t)(uint32_t)wbuf[kk * 4 + 3] << 32);
      bf16x8 a = __builtin_bit_cast(bf16x8, v);
#pragma unroll
      for (int nt = 0; nt < 4; ++nt)
        acc[nt] = __builtin_amdgcn_mfma_f32_16x16x32_bf16(a, bfr[kk][nt], acc[nt], 0, 0, 0);
    }
    {
      int crow = hi * 4;  // C layout: col=lane&15, row=(lane>>4)*4+r
#pragma unroll
      for (int nt = 0; nt < 4; ++nt)
#pragma unroll
        for (int r = 0; r < 4; ++r) xchg[wave][crow + r][nt * 16 + lm] = acc[nt][r];
    }
    BAR_LDS();  // xchg writes visible; NO vmcnt drain (stores stay in flight)

    if (tid < 256) {
      float raw[4];
#pragma unroll
      for (int g = 0; g < 4; ++g) {
        int c = g * 16 + u;
        float s = xchg[0][r_b][c];
#pragma unroll
        for (int w = 1; w < 8; ++w) s += xchg[w][r_b][c];
        raw[g] = s;
      }
      float ig = sigm(raw[0] + b2f(xr0));
      float fg = sigm(raw[1] + b2f(xr1));
      float gg = tanh_(raw[2] + b2f(xr2));
      float og = sigm(raw[3] + b2f(xr3));
      c_val = fg * c_val + ig * gg;
      float h_new = og * tanh_(c_val);
      // tagged store: ONE atomic u64 = payload pair | (t+1)<<32 (never drained
      // in-loop; tags self-validate at the consumer)
      uint32_t mine = f2b(h_new);
      uint32_t other = __shfl_xor(mine, 1);
      if ((u & 1) == 0) {
        uint64_t word = (uint64_t)(mine | (other << 16)) | ((uint64_t)(uint32_t)(t + 1) << 32);
        __hip_atomic_store(
            h_tag + ((size_t)(t & 1) * 64 + b) * 512 + (unit >> 1), word,
            __ATOMIC_RELAXED, __HIP_MEMORY_SCOPE_AGENT);
      }
      out_h[(size_t)t * 65536 + (size_t)b * 1024 + unit] = h_new;
      if (t == 511) {
        out_hT[b * 1024 + unit] = h_new;
        out_cT[b * 1024 + unit] = c_val;
      }
    }
    BAR_LDS();  // xchg WAR; again no vmcnt drain (out_h ack not awaited)
  }

  if (tid < 256) c_st[b * 1024 + unit] = c_val;
}

// -------------------------------------------------------------------- launch
extern "C" void kernel_launch(void* const* d_in, const int* in_sizes, int n_in,
                              void* d_out, int out_size, void* d_ws, size_t ws_size,
                              hipStream_t stream) {
  const float* x = (const float*)d_in[0];
  const float* h0 = (const float*)d_in[1];
  const float* c0 = (const float*)d_in[2];
  const float* wih = (const float*)d_in[3];
  const float* whh = (const float*)d_in[4];
  const float* bias = (const float*)d_in[5];

  float* out = (float*)d_out;
  float* out_h = out;                              // [512][64][1024]
  float* out_hT = out + (size_t)512 * 64 * 1024;   // [64][1024]
  float* out_cT = out_hT + 64 * 1024;              // [64][1024]

  // adaptive xg window (bf16): W in {64,16,4}
  const size_t fixed = (size_t)2 * 4096 * 1024 * 2    // wih_t + whh_t
                       + (size_t)2 * 64 * 512 * 8     // h_tag (512KB)
                       + (size_t)64 * 1024 * 4;       // c_state
  int W = 64;
  while (W > 4 && fixed + (size_t)W * 64 * 4096 * 2 > ws_size) W >>= 2;

  char* ws = (char*)d_ws;
  u16* wih_t = (u16*)ws;     ws += (size_t)4096 * 1024 * 2;    // 8MB
  u16* whh_t = (u16*)ws;     ws += (size_t)4096 * 1024 * 2;    // 8MB
  u16* xg = (u16*)ws;        ws += (size_t)W * 64 * 4096 * 2;  // <=32MB
  uint64_t* h_tag = (uint64_t*)ws; ws += (size_t)2 * 64 * 512 * 8;  // 512KB
  float* c_st = (float*)ws;                                    // 256KB

  // tags must start below any future t (0xAA poison / replay staleness)
  hipMemsetAsync(h_tag, 0, (size_t)2 * 64 * 512 * 8, stream);
  convert_h0<<<128, 256, 0, stream>>>(h0, h_tag + (size_t)64 * 512);  // buf 1
  hipMemcpyAsync(c_st, c0, (size_t)64 * 1024 * 4, hipMemcpyDeviceToDevice, stream);
  transpose_w<<<dim3(64, 16, 2), 256, 0, stream>>>(wih, whh, wih_t, whh_t);

  for (int t0 = 0; t0 < 512; t0 += W) {
    gemm_xg<<<dim3(32, W / 2), 256, 0, stream>>>(x + (size_t)t0 * 64 * 1024, wih_t, bias, xg);
    int t0c = t0, Wc = W;
    void* args[] = {(void*)&xg,    (void*)&whh_t,  (void*)&h_tag, (void*)&c_st,
                    (void*)&out_h, (void*)&out_hT, (void*)&out_cT,
                    (void*)&t0c,   (void*)&Wc};
    hipLaunchCooperativeKernel((const void*)recur_pers, dim3(256), dim3(512), args, 0,
                               stream);
  }
}